// Round 1
// baseline (1284.601 us; speedup 1.0000x reference)
//
#include <hip/hip_runtime.h>
#include <stdint.h>

typedef float f32x4 __attribute__((ext_vector_type(4)));
typedef short bf16x8 __attribute__((ext_vector_type(8)));

#define BM 128
#define BN 128
#define BK 32
#define LDA 40   // LDS row stride in bf16 elems (80 B => 16B-aligned rows, ~2-way banks)

__device__ __forceinline__ uint32_t pack_bf16(float a, float b) {
  // round-half-up truncation to bf16, packed (a->low16, b->high16)
  uint32_t ua = __builtin_bit_cast(uint32_t, a);
  uint32_t ub = __builtin_bit_cast(uint32_t, b);
  ua += 0x8000u;
  ub += 0x8000u;
  return (ua >> 16) | (ub & 0xffff0000u);
}

// C = A(MxK) * B(KxN) [+ bias, + optional interleaved SwiGLU -> bf16 out]
// A: row-major, k-contiguous (fp32 or bf16 per A_BF16). B: row-major fp32, n-contiguous.
// One block: 128x128 tile, 4 waves in 2x2, each wave 64x64 via 4x4 MFMA 16x16x32 tiles.
template<bool A_BF16, bool SWIGLU>
__global__ __launch_bounds__(256)
void gemm_fused(const void* __restrict__ Aall,
                const float* __restrict__ Ball,
                const float* __restrict__ biasall,
                void* __restrict__ Outall,
                int M, int N, int K,
                long sA, long sB, long sBias, long sOut)
{
  __shared__ __align__(16) unsigned short As[BM * LDA];  // As[m][k]
  __shared__ __align__(16) unsigned short Bs[BN * LDA];  // Bs[n][k]  (B transposed)

  const int e    = blockIdx.z;
  const int m0   = blockIdx.y * BM;
  const int n0   = blockIdx.x * BN;
  const int tid  = threadIdx.x;
  const int lane = tid & 63;
  const int q    = lane >> 4;      // quad 0..3
  const int c    = lane & 15;      // col-in-tile 0..15
  const int wave = tid >> 6;
  const int wm   = (wave >> 1) * 64;
  const int wn   = (wave & 1) * 64;

  // A staging: thread -> (row ar, 16-elem k-chunk ah)
  const int ar = tid >> 1;
  const int ah = (tid & 1) * 16;
  // B staging: thread -> 4 k-rows starting bkg, 4 n-cols {bng + 32*jj}
  const int bkg = (tid >> 5) * 4;  // 0,4,...,28
  const int bng = tid & 31;

  const float* Bbase = Ball + e * sB + (long)bkg * N + (n0 + bng);

  const float*          A32 = nullptr;
  const unsigned short* A16 = nullptr;
  if (A_BF16) A16 = (const unsigned short*)Aall + e * sA + (long)(m0 + ar) * K + ah;
  else        A32 = (const float*)Aall          + e * sA + (long)(m0 + ar) * K + ah;

  f32x4 acc[4][4];
#pragma unroll
  for (int i = 0; i < 4; i++)
#pragma unroll
    for (int j = 0; j < 4; j++)
      acc[i][j] = (f32x4){0.f, 0.f, 0.f, 0.f};

  for (int k0 = 0; k0 < K; k0 += BK) {
    __syncthreads();  // protect previous iteration's fragment reads

    // ---- stage A tile (128 x 32) ----
    uint32_t ad[8];
    if (A_BF16) {
      const uint4* p = (const uint4*)(A16 + k0);
      uint4 u0 = p[0], u1 = p[1];
      ad[0] = u0.x; ad[1] = u0.y; ad[2] = u0.z; ad[3] = u0.w;
      ad[4] = u1.x; ad[5] = u1.y; ad[6] = u1.z; ad[7] = u1.w;
    } else {
      const float4* p = (const float4*)(A32 + k0);
      float4 f0 = p[0], f1 = p[1], f2 = p[2], f3 = p[3];
      ad[0] = pack_bf16(f0.x, f0.y); ad[1] = pack_bf16(f0.z, f0.w);
      ad[2] = pack_bf16(f1.x, f1.y); ad[3] = pack_bf16(f1.z, f1.w);
      ad[4] = pack_bf16(f2.x, f2.y); ad[5] = pack_bf16(f2.z, f2.w);
      ad[6] = pack_bf16(f3.x, f3.y); ad[7] = pack_bf16(f3.z, f3.w);
    }
    {
      uint4* dstA = (uint4*)&As[ar * LDA + ah];  // 80*ar + 32*(tid&1) bytes: 16B aligned
      dstA[0] = make_uint4(ad[0], ad[1], ad[2], ad[3]);
      dstA[1] = make_uint4(ad[4], ad[5], ad[6], ad[7]);
    }

    // ---- stage B tile (32 x 128) transposed into Bs[n][k] ----
    {
      const float* Bp = Bbase + (long)k0 * N;
#pragma unroll
      for (int jj = 0; jj < 4; jj++) {
        float v0 = Bp[(long)0 * N + 32 * jj];
        float v1 = Bp[(long)1 * N + 32 * jj];
        float v2 = Bp[(long)2 * N + 32 * jj];
        float v3 = Bp[(long)3 * N + 32 * jj];
        uint2 w;
        w.x = pack_bf16(v0, v1);
        w.y = pack_bf16(v2, v3);
        *(uint2*)&Bs[(bng + 32 * jj) * LDA + bkg] = w;  // 80*n + 8*kg/..: 8B aligned
      }
    }

    __syncthreads();

    // ---- fragments + MFMA ----
    bf16x8 af[4], bfr[4];
#pragma unroll
    for (int i = 0; i < 4; i++)
      af[i] = *(const bf16x8*)&As[(wm + i * 16 + c) * LDA + q * 8];
#pragma unroll
    for (int j = 0; j < 4; j++)
      bfr[j] = *(const bf16x8*)&Bs[(wn + j * 16 + c) * LDA + q * 8];
#pragma unroll
    for (int i = 0; i < 4; i++)
#pragma unroll
      for (int j = 0; j < 4; j++)
        acc[i][j] = __builtin_amdgcn_mfma_f32_16x16x32_bf16(af[i], bfr[j], acc[i][j], 0, 0, 0);
  }

  // ---- epilogue ----
  if (SWIGLU) {
    unsigned short* H = (unsigned short*)Outall + e * sOut;
    const int ldh = N >> 1;
#pragma unroll
    for (int j = 0; j < 4; j++) {
      const int f = n0 + wn + j * 16 + c;
      const float bias = biasall[e * sBias + f];
#pragma unroll
      for (int i = 0; i < 4; i++) {
        const int rb = m0 + wm + i * 16 + q * 4;
#pragma unroll
        for (int r = 0; r < 4; r++) {
          float v = acc[i][j][r] + bias;
          float p = __shfl_xor(v, 1);       // partner column (f^1), same row
          float xg = (f & 1) ? p : v;
          float xl = (f & 1) ? v : p;
          xg = fminf(xg, 7.f);
          xl = fminf(fmaxf(xl, -7.f), 7.f);
          float sig = 1.f / (1.f + __expf(-1.702f * xg));
          float res = xg * sig * (xl + 1.f);
          if ((f & 1) == 0) {
            uint32_t ub = __builtin_bit_cast(uint32_t, res) + 0x8000u;
            H[(long)(rb + r) * ldh + (f >> 1)] = (unsigned short)(ub >> 16);
          }
        }
      }
    }
  } else {
    float* O = (float*)Outall + e * sOut;
#pragma unroll
    for (int j = 0; j < 4; j++) {
      const int col = n0 + wn + j * 16 + c;
      const float bias = biasall[e * sBias + col];
#pragma unroll
      for (int i = 0; i < 4; i++) {
        const int rb = m0 + wm + i * 16 + q * 4;
#pragma unroll
        for (int r = 0; r < 4; r++)
          O[(long)(rb + r) * N + col] = acc[i][j][r] + bias;
      }
    }
  }
}

extern "C" void kernel_launch(void* const* d_in, const int* in_sizes, int n_in,
                              void* d_out, int out_size, void* d_ws, size_t ws_size,
                              hipStream_t stream) {
  const float* x  = (const float*)d_in[0];   // (E,T,D)
  const float* w1 = (const float*)d_in[1];   // (E,D,2D)
  const float* b1 = (const float*)d_in[2];   // (E,2D)
  const float* w2 = (const float*)d_in[3];   // (E,D,D)
  const float* b2 = (const float*)d_in[4];   // (E,D)
  float* out = (float*)d_out;                // (E,T,D) fp32
  unsigned short* h = (unsigned short*)d_ws; // (E,T,D) bf16 intermediate: 64 MiB

  const int E = 8, T = 2048, D = 2048;
  dim3 blk(256);

  // GEMM1: (T x D) * (D x 2D) + b1 -> SwiGLU -> h (T x D) bf16
  dim3 g1((2 * D) / BN, T / BM, E);
  gemm_fused<false, true><<<g1, blk, 0, stream>>>(
      x, w1, b1, h,
      T, 2 * D, D,
      (long)T * D, (long)D * 2 * D, (long)2 * D, (long)T * D);

  // GEMM2: (T x D) * (D x D) + b2 -> out fp32
  dim3 g2(D / BN, T / BM, E);
  gemm_fused<true, false><<<g2, blk, 0, stream>>>(
      h, w2, b2, out,
      T, D, D,
      (long)T * D, (long)D * D, (long)D, (long)T * D);
}